// Round 7
// baseline (1770.790 us; speedup 1.0000x reference)
//
#include <hip/hip_runtime.h>
#include <hip/hip_bf16.h>
#include <cstdint>

// Problem constants
#define NB     16384   // batch
#define DIN    1024
#define HID    2048
#define NE     8
#define NC     8
#define DZ     256

// R12 main GEMM: 256x256 block tile, 8 waves (2M x 4N), wave tile 128x64,
// BK=64.  A: LDS, TRIPLE-buffered (3x32KB), staged 2 tiles ahead via
// global_load_lds.  B: global->register, double-buffered sets (2x8 frags).
// Per-round protocol: WAITV(12) counted (12 vm ops/round -> ~2 rounds slack
// for both A-DMA and B-loads; R9's failure was WAITV(0) = 600cyc slack),
// WAITV(0) only at each chunk's last round.  One barrier per round.
// Rationale (R11 post-mortem): rounds measured 5053 cyc = MFMA 2483 + LDS
// 2570 SERIALIZED (lockstep waves + full register file).  Moving B off the
// LDS port cuts LDS to ~160KB/round (<2483cyc) and B rides the idle L1/L2
// vector path with latency hidden by the counted wait.
#define BK2    64
#define NKT    (DIN / BK2)   // 16
#define GRID_MAIN 256        // 1 block/CU persistent

typedef short bf16x8 __attribute__((ext_vector_type(8)));
typedef float f32x4  __attribute__((ext_vector_type(4)));

__device__ __forceinline__ unsigned short f2bf(float f) {
    unsigned int u = __float_as_uint(f);
    unsigned int r = (u + 0x7FFFu + ((u >> 16) & 1u)) >> 16;
    return (unsigned short)r;
}

__device__ __forceinline__ void async_copy16(const void* g, void* l) {
    __builtin_amdgcn_global_load_lds(
        (const __attribute__((address_space(1))) unsigned int*)g,
        (__attribute__((address_space(3))) unsigned int*)l, 16, 0, 0);
}

// ---------------------------------------------------------------------------
// Fused pre-pass: blocks [0,NB) do LayerNorm->bf16 xhat (one block/row);
// blocks [NB, NB+NB/4) do the gate (4 rows/block) and fold b2 into logits.
// ---------------------------------------------------------------------------
__global__ __launch_bounds__(256) void k_pre(const float* __restrict__ feat,
                                             unsigned short* __restrict__ xhat,
                                             const float* __restrict__ z,
                                             const float* __restrict__ mu,
                                             const int* __restrict__ tau_i,
                                             const float* __restrict__ b2,
                                             float* __restrict__ wout,
                                             float* __restrict__ logits) {
    if (blockIdx.x < NB) {
        // ---- LayerNorm (shared part) ----
        int row = blockIdx.x;
        int t = threadIdx.x;
        float4 v = *(const float4*)&feat[(size_t)row * DIN + t * 4];
        float s  = v.x + v.y + v.z + v.w;
        float sq = v.x * v.x + v.y * v.y + v.z * v.z + v.w * v.w;
#pragma unroll
        for (int off = 32; off; off >>= 1) {
            s  += __shfl_down(s, off);
            sq += __shfl_down(sq, off);
        }
        __shared__ float ls[8];
        int w = t >> 6, l = t & 63;
        if (l == 0) { ls[w] = s; ls[4 + w] = sq; }
        __syncthreads();
        s  = ls[0] + ls[1] + ls[2] + ls[3];
        sq = ls[4] + ls[5] + ls[6] + ls[7];
        float mean = s * (1.f / DIN);
        float var  = sq * (1.f / DIN) - mean * mean;
        float r = 1.0f / sqrtf(var + 1e-5f);
        uint2 p;
        p.x = (unsigned)f2bf((v.x - mean) * r) | ((unsigned)f2bf((v.y - mean) * r) << 16);
        p.y = (unsigned)f2bf((v.z - mean) * r) | ((unsigned)f2bf((v.w - mean) * r) << 16);
        *(uint2*)&xhat[(size_t)row * DIN + t * 4] = p;
    } else {
        // ---- gate: softmax(cos_sim(z,mu)/tau); logits init = sum_e w*b2 ----
        int row = (blockIdx.x - NB) * 4 + (threadIdx.x >> 6);
        int l = threadIdx.x & 63;
        float4 zv = *(const float4*)&z[(size_t)row * DZ + l * 4];
        float zz = zv.x * zv.x + zv.y * zv.y + zv.z * zv.z + zv.w * zv.w;
        float dots[NE], mm[NE];
#pragma unroll
        for (int e = 0; e < NE; ++e) {
            float4 m = *(const float4*)&mu[e * DZ + l * 4];
            dots[e] = zv.x * m.x + zv.y * m.y + zv.z * m.z + zv.w * m.w;
            mm[e]   = m.x * m.x + m.y * m.y + m.z * m.z + m.w * m.w;
        }
#pragma unroll
        for (int off = 32; off; off >>= 1) {
            zz += __shfl_xor(zz, off);
#pragma unroll
            for (int e = 0; e < NE; ++e) {
                dots[e] += __shfl_xor(dots[e], off);
                mm[e]   += __shfl_xor(mm[e], off);
            }
        }
        float zn = fmaxf(sqrtf(zz), 1e-12f);
        float tau = fmaxf(1e-6f, (float)tau_i[0]);
        float s[NE], mx = -1e30f;
#pragma unroll
        for (int e = 0; e < NE; ++e) {
            s[e] = dots[e] / (zn * fmaxf(sqrtf(mm[e]), 1e-12f)) / tau;
            mx = fmaxf(mx, s[e]);
        }
        float sum = 0.f;
#pragma unroll
        for (int e = 0; e < NE; ++e) { s[e] = expf(s[e] - mx); sum += s[e]; }
        float inv = 1.f / sum;
        if (l < NE) {
            wout[(size_t)row * NE + l] = s[l] * inv;
            float acc = 0.f;
#pragma unroll
            for (int e = 0; e < NE; ++e) acc += s[e] * inv * b2[e * NC + l];
            logits[(size_t)row * NC + l] = acc;
        }
    }
}

// ---------------------------------------------------------------------------
// W2 transpose->bf16 (padded [E][16][HID]) and b1p init.
// ---------------------------------------------------------------------------
__global__ __launch_bounds__(256) void k_w2prep(const float* __restrict__ W2,
                                                const float* __restrict__ b1,
                                                unsigned short* __restrict__ w2t,
                                                float* __restrict__ b1p) {
    int i = blockIdx.x * 256 + threadIdx.x;   // 8*16*2048 = 262144
    int e = i >> 15;
    int rem = i & 32767;
    int c = rem >> 11;
    int h = rem & 2047;
    float v = (c < NC) ? W2[((size_t)(e * HID + h)) * NC + c] : 0.f;
    w2t[i] = f2bf(v);
    if (i < NE * HID) b1p[i] = b1[i];
}

// ---------------------------------------------------------------------------
// W1 fold+transpose: W1t[e][h][d] = bf16(gamma[e][d] * W1[e][d][h]);
// b1p[e][h] += sum_d beta[e][d]*W1[e][d][h].  64x64 LDS tile transpose.
// ---------------------------------------------------------------------------
__global__ __launch_bounds__(256) void k_w1prep(const float* __restrict__ W1,
                                                const float* __restrict__ gamma,
                                                const float* __restrict__ beta,
                                                unsigned short* __restrict__ w1t,
                                                float* __restrict__ b1p) {
    __shared__ float tile[64][65];   // [h-local][d-local], unscaled
    int e  = blockIdx.z;
    int d0 = blockIdx.y * 64;
    int h0 = blockIdx.x * 64;
    int tx = threadIdx.x & 15, ty = threadIdx.x >> 4;
#pragma unroll
    for (int rr = 0; rr < 4; ++rr) {
        int d = ty + rr * 16;
        float4 v = *(const float4*)&W1[((size_t)e * DIN + d0 + d) * HID + h0 + tx * 4];
        tile[tx * 4 + 0][d] = v.x;
        tile[tx * 4 + 1][d] = v.y;
        tile[tx * 4 + 2][d] = v.z;
        tile[tx * 4 + 3][d] = v.w;
    }
    __syncthreads();
    float4 g = *(const float4*)&gamma[(size_t)e * DIN + d0 + tx * 4];
#pragma unroll
    for (int rr = 0; rr < 4; ++rr) {
        int h = ty + rr * 16;
        uint2 p;
        p.x = (unsigned)f2bf(tile[h][tx * 4 + 0] * g.x) |
              ((unsigned)f2bf(tile[h][tx * 4 + 1] * g.y) << 16);
        p.y = (unsigned)f2bf(tile[h][tx * 4 + 2] * g.z) |
              ((unsigned)f2bf(tile[h][tx * 4 + 3] * g.w) << 16);
        *(uint2*)&w1t[((size_t)e * HID + h0 + h) * DIN + d0 + tx * 4] = p;
    }
    if (threadIdx.x < 64) {
        int h = threadIdx.x;
        float sacc = 0.f;
        for (int r = 0; r < 64; ++r)
            sacc += beta[(size_t)e * DIN + d0 + r] * tile[h][r];
        atomicAdd(&b1p[(size_t)e * HID + h0 + h], sacc);
    }
}

// ---------------------------------------------------------------------------
// Fused main kernel, R12.
// Per round (tile g): {WAITV(12) [completes tile g's A-DMA + B-loads, both
// issued at round g-2]; BAR [publishes A buf g%3]; ISSA(tile g+2 -> buf
// (g+2)%3); COMP (16 ds_read + 64 MFMA, B from reg set g&1); ISSB(tile g+2
// -> same reg set, AFTER its last read)}.  Rounds flow across chunk/pr
// boundaries (round 14/15 issue the next chunk's tiles 0/1); only the
// chunk-tail round uses WAITV(0).  Epilogue ht is in its own LDS region
// (no buffer overlay -> no drain); epilogue's bias/w2t loads briefly drain
// vmcnt via compiler waits (~500cyc x16, accepted).
// WAR on A bufs: tile g+2's DMA (issued after round g's BAR) targets buf
// (g+2)%3, last read in round g-1; every wave's round g-1 reads completed
// before it passed round g's BAR (its last MFMA forced lgkmcnt). Safe.
// ---------------------------------------------------------------------------

#define WAITV(n_) asm volatile("s_waitcnt vmcnt(" #n_ ")" ::: "memory")
#define BAR()  do { __builtin_amdgcn_s_barrier(); __builtin_amdgcn_sched_barrier(0); } while (0)

// A-stage: 256x64 tile (32KB), 4 copies/thread, into buffer bIdx_ (0..2).
// Thread t covers rows 64n+(t>>3), phys chunk (t&7) <- logical (t&7)^(row&7).
#define ISSA(gAp_, kt_, bIdx_) do {                                           \
    char* da_ = (char*)lds + (bIdx_) * 32768 + (t << 4);                      \
    const size_t ko_ = sbase + (size_t)(kt_) * BK2;                           \
    async_copy16((gAp_) + ko_,          da_);                                 \
    async_copy16((gAp_) + ko_ + 65536,  da_ + 8192);                          \
    async_copy16((gAp_) + ko_ + 131072, da_ + 16384);                         \
    async_copy16((gAp_) + ko_ + 196608, da_ + 24576);                         \
} while (0)

// B-load: 8 frags (4 j x 2 k-halves) of k-tile kt_ into register set SET_.
#define ISSB(SET_, gBp_, kt_) do {                                            \
    const size_t kb_ = (size_t)(kt_) * BK2;                                   \
    _Pragma("unroll")                                                         \
    for (int j_ = 0; j_ < 4; ++j_) {                                          \
        SET_[j_]     = *(const bf16x8*)&(gBp_)[bOff[j_] + kb_];               \
        SET_[4 + j_] = *(const bf16x8*)&(gBp_)[bOff[j_] + kb_ + 32];          \
    }                                                                         \
} while (0)

// 64 MFMA on A buffer at base_, B from reg set SET_ (two k-halves).
#define COMP(base_, SET_) do {                                                \
    const short* la_ = (const short*)(base_);                                 \
    __builtin_amdgcn_s_setprio(1);                                            \
    _Pragma("unroll")                                                         \
    for (int i_ = 0; i_ < 8; ++i_) {                                          \
        const bf16x8 aF_ = *(const bf16x8*)&la_[(wm + 16 * i_ + ml) * 64 + csw0]; \
        _Pragma("unroll")                                                     \
        for (int j_ = 0; j_ < 4; ++j_)                                        \
            acc[i_][j_] = __builtin_amdgcn_mfma_f32_16x16x32_bf16(            \
                aF_, SET_[j_], acc[i_][j_], 0, 0, 0);                         \
    }                                                                         \
    _Pragma("unroll")                                                         \
    for (int i_ = 0; i_ < 8; ++i_) {                                          \
        const bf16x8 aF_ = *(const bf16x8*)&la_[(wm + 16 * i_ + ml) * 64 + (csw0 ^ 32)]; \
        _Pragma("unroll")                                                     \
        for (int j_ = 0; j_ < 4; ++j_)                                        \
            acc[i_][j_] = __builtin_amdgcn_mfma_f32_16x16x32_bf16(            \
                aF_, SET_[4 + j_], acc[i_][j_], 0, 0, 0);                     \
    }                                                                         \
    __builtin_amdgcn_s_setprio(0);                                            \
} while (0)

__global__ __launch_bounds__(512, 2) void moe_main(
        const unsigned short* __restrict__ xhat,   // [B][DIN] bf16
        const unsigned short* __restrict__ w1t,    // [E][HID][DIN] bf16
        const float* __restrict__ b1p,             // [E][HID]
        const unsigned short* __restrict__ w2t,    // [E][16][HID] bf16 (c>=8 zero)
        const float* __restrict__ wg,              // [B][NE]
        float* __restrict__ logits) {              // [B][NC]
    // LDS: [0,96K) A bufs x3; [96K,136K) per-wave ht; [136K,152K) red
    __shared__ __align__(16) char lds[155648];

    const int t  = threadIdx.x;
    const int w  = t >> 6, l = t & 63;
    const int q  = l >> 4, ml = l & 15;
    const int wm = (w >> 2) * 128;       // wave's hid offset in 256 tile
    const int wn = (w & 3) * 64;         // wave's batch offset in 256 tile
    const int csw0 = (q ^ (ml & 7)) * 8; // swizzled A frag chunk, k-half 0
    const size_t sbase = (size_t)(t >> 3) * DIN +
                         (size_t)(((t & 7) ^ ((t >> 3) & 7)) * 8);

    const int e    = blockIdx.x & 7;     // expert == XCD (bid%8 -> XCD)
    const int slot = blockIdx.x >> 3;    // 0..31
    char* myht = (char*)lds + 98304 + w * 5120;  // per-wave 64x80B hT
    const unsigned short* eA = w1t + (size_t)e * HID * DIN;

    // per-lane B row offsets (within a pr's 256-row tile)
    size_t bOff[4];
#pragma unroll
    for (int j = 0; j < 4; ++j)
        bOff[j] = (size_t)(wn + 16 * j + ml) * DIN + q * 8;

    bf16x8 B0[8], B1[8];
    int bcur = 0;   // A buffer index of the CURRENT tile (g % 3)

    // prologue: issue tiles 0 and 1 of (pr0, ms0)
    {
        const unsigned short* gB0 = xhat + (size_t)(slot * 256) * DIN;
        ISSA(eA, 0, 0); ISSB(B0, gB0, 0);
        ISSA(eA, 1, 1); ISSB(B1, gB0, 1);
    }

    for (int pr = 0; pr < 2; ++pr) {
        const int b0 = (pr * 32 + slot) * 256;
        const unsigned short* gB = xhat + (size_t)b0 * DIN;

        f32x4 acc2[4];
#pragma unroll
        for (int tb = 0; tb < 4; ++tb) acc2[tb] = (f32x4){0.f, 0.f, 0.f, 0.f};

        for (int ms = 0; ms < 8; ++ms) {
            const int hid0 = ms * 256;
            const unsigned short* gA = eA + (size_t)hid0 * DIN;
            const bool last = (pr == 1) && (ms == 7);
            // next chunk's panels (unused when last)
            const unsigned short* gAn = (ms == 7) ? eA : gA + (size_t)256 * DIN;
            const unsigned short* gBn = (ms == 7)
                ? xhat + (size_t)(((pr + 1) * 32 + slot) * 256) * DIN : gB;

            f32x4 acc[8][4];
#pragma unroll
            for (int i = 0; i < 8; ++i)
#pragma unroll
                for (int j = 0; j < 4; ++j) acc[i][j] = (f32x4){0.f, 0.f, 0.f, 0.f};

#pragma unroll 1
            for (int kp = 0; kp < 8; ++kp) {
                // ---- even tile kt=2kp (reg set B0) ----
                WAITV(12);     // tile 2kp (A+B) complete; g+1,g+2 in flight
                BAR();
                {
                    int bi = bcur + 2; if (bi >= 3) bi -= 3;
                    if (kp < 7)      ISSA(gA, 2 * kp + 2, bi);
                    else if (!last)  ISSA(gAn, 0, bi);
                }
                COMP((char*)lds + bcur * 32768, B0);
                if (kp < 7)      ISSB(B0, gB, 2 * kp + 2);
                else if (!last)  ISSB(B0, gBn, 0);
                bcur = (bcur == 2) ? 0 : bcur + 1;

                // ---- odd tile kt=2kp+1 (reg set B1) ----
                if (kp == 7) { WAITV(0); }   // chunk tail: full drain
                else         { WAITV(12); }
                BAR();
                {
                    int bi = bcur + 2; if (bi >= 3) bi -= 3;
                    if (kp < 7)      ISSA(gA, 2 * kp + 3, bi);
                    else if (!last)  ISSA(gAn, 1, bi);
                }
                COMP((char*)lds + bcur * 32768, B1);
                if (kp < 7)      ISSB(B1, gB, 2 * kp + 3);
                else if (!last)  ISSB(B1, gBn, 1);
                bcur = (bcur == 2) ? 0 : bcur + 1;
            }

            // ---- epilogue: bias+ReLU -> ht (own LDS region, wave-private),
            //      second GEMM over 32-hid slabs into acc2 ----
#pragma unroll
            for (int s = 0; s < 4; ++s) {
#pragma unroll
                for (int i2 = 0; i2 < 2; ++i2) {
                    const int i = 2 * s + i2;
                    const float4 bias = *(const float4*)
                        &b1p[(size_t)e * HID + hid0 + wm + 16 * i + 4 * q];
#pragma unroll
                    for (int j = 0; j < 4; ++j) {
                        float v0 = fmaxf(acc[i][j].x + bias.x, 0.f);
                        float v1 = fmaxf(acc[i][j].y + bias.y, 0.f);
                        float v2 = fmaxf(acc[i][j].z + bias.z, 0.f);
                        float v3 = fmaxf(acc[i][j].w + bias.w, 0.f);
                        uint2 p;
                        p.x = (unsigned)f2bf(v0) | ((unsigned)f2bf(v1) << 16);
                        p.y = (unsigned)f2bf(v2) | ((unsigned)f2bf(v3) << 16);
                        *(uint2*)(myht + (16 * j + ml) * 80 + (16 * i2 + 4 * q) * 2) = p;
                    }
                }
                const bf16x8 b2f = *(const bf16x8*)&w2t[((size_t)e * 16 + ml) * HID +
                                                        hid0 + wm + 32 * s + 8 * q];
#pragma unroll
                for (int tb = 0; tb < 4; ++tb) {
                    const bf16x8 a2f =
                        *(const bf16x8*)(myht + (16 * tb + ml) * 80 + q * 16);
                    acc2[tb] = __builtin_amdgcn_mfma_f32_16x16x32_bf16(
                        a2f, b2f, acc2[tb], 0, 0, 0);
                }
            }
        }

        // ---- cross-wave (hid-half) reduction of acc2, gated atomic store ----
        __syncthreads();   // also drains vm (next-pr prefetch completes; OK)
        float* red = (float*)(lds + 139264);
        if (w >= 4) {
            float* dst = red + ((w & 3) * 64 + l) * 16;
#pragma unroll
            for (int tb = 0; tb < 4; ++tb)
#pragma unroll
                for (int r = 0; r < 4; ++r) dst[tb * 4 + r] = acc2[tb][r];
        }
        __syncthreads();
        if (w < 4) {
            const float* src = red + (w * 64 + l) * 16;
            if (ml < NC) {
#pragma unroll
                for (int tb = 0; tb < 4; ++tb) {
#pragma unroll
                    for (int r = 0; r < 4; ++r) {
                        float v = acc2[tb][r] + src[tb * 4 + r];
                        const int bg = b0 + wn + 16 * tb + 4 * q + r;
                        atomicAdd(&logits[(size_t)bg * NC + ml],
                                  wg[(size_t)bg * NE + e] * v);
                    }
                }
            }
        }
        // next pr's first round: WAITV no-ops (tiles already complete). Safe.
    }
}

// ---------------------------------------------------------------------------
extern "C" void kernel_launch(void* const* d_in, const int* in_sizes, int n_in,
                              void* d_out, int out_size, void* d_ws, size_t ws_size,
                              hipStream_t stream) {
    const float* feat  = (const float*)d_in[0];
    const float* z     = (const float*)d_in[1];
    const float* mu    = (const float*)d_in[2];
    const float* gamma = (const float*)d_in[3];
    const float* beta  = (const float*)d_in[4];
    const float* W1    = (const float*)d_in[5];
    const float* b1    = (const float*)d_in[6];
    const float* W2    = (const float*)d_in[7];
    const float* b2    = (const float*)d_in[8];
    const int*   tau   = (const int*)d_in[9];

    float* logits = (float*)d_out;                 // [B][NC]
    float* wout   = logits + (size_t)NB * NC;      // [B][NE]

    char* ws = (char*)d_ws;
    unsigned short* xhat = (unsigned short*)ws;                       // 33.5 MB
    unsigned short* w1t  = (unsigned short*)(ws + 33554432);          // 33.5 MB
    unsigned short* w2t  = (unsigned short*)(ws + 67108864);          // 0.5 MB
    float*          b1p  = (float*)(ws + 67633152);                   // 64 KB

    k_pre<<<NB + NB / 4, 256, 0, stream>>>(feat, xhat, z, mu, tau, b2, wout, logits);
    k_w2prep<<<(NE * 16 * HID) / 256, 256, 0, stream>>>(W2, b1, w2t, b1p);
    k_w1prep<<<dim3(HID / 64, DIN / 64, NE), 256, 0, stream>>>(W1, gamma, beta, w1t, b1p);
    moe_main<<<dim3(GRID_MAIN), 512, 0, stream>>>(xhat, w1t, b1p, w2t, wout, logits);
}